// Round 13
// baseline (151.979 us; speedup 1.0000x reference)
//
#include <hip/hip_runtime.h>
#include <hip/hip_fp16.h>
#include <math.h>

#define NN 4096
#define FIN 20
#define NH 4
#define DH 64
#define ALPHA 0.2f

typedef _Float16 f16x8 __attribute__((ext_vector_type(8)));
typedef _Float16 f16x4 __attribute__((ext_vector_type(4)));
typedef __fp16 fp16x2 __attribute__((ext_vector_type(2)));
typedef float f32x4 __attribute__((ext_vector_type(4)));

__device__ inline void gload_lds16(const void* gsrc, void* ldsbase) {
    __builtin_amdgcn_global_load_lds(
        (const __attribute__((address_space(1))) void*)gsrc,
        (__attribute__((address_space(3))) void*)ldsbase, 16, 0, 0);
}

// ---- fused front kernel: pack (blocks 0..8191) | l0wh (8192..8447) | w1t (8448..8703)
__global__ __launch_bounds__(256) void k_front(const int* __restrict__ adj,
        unsigned char* __restrict__ bits, const float* __restrict__ x,
        const float* __restrict__ W0, const float* __restrict__ a0,
        _Float16* __restrict__ whT, float* __restrict__ fs, float* __restrict__ fd,
        const float* __restrict__ W1, _Float16* __restrict__ w1T) {
    __shared__ float xs[16 * FIN];
    const int bid = blockIdx.x;
    const int tid = threadIdx.x;
    if (bid < 8192) {
        int t = bid * 256 + tid;
        const int4* p = (const int4*)(adj + (size_t)t * 8);
        int4 a = p[0], b = p[1];
        unsigned int byte = 0;
        byte |= (a.x > 0) << 0; byte |= (a.y > 0) << 1;
        byte |= (a.z > 0) << 2; byte |= (a.w > 0) << 3;
        byte |= (b.x > 0) << 4; byte |= (b.y > 0) << 5;
        byte |= (b.z > 0) << 6; byte |= (b.w > 0) << 7;
        bits[t] = (unsigned char)byte;
    } else if (bid < 8448) {
        int n0 = (bid - 8192) * 16;
        for (int i = tid; i < 16 * FIN; i += 256) xs[i] = x[n0 * FIN + i];
        __syncthreads();
        int h = tid >> 6, d = tid & 63;
        float w0r[FIN];
#pragma unroll
        for (int f = 0; f < FIN; ++f) w0r[f] = W0[(h * FIN + f) * DH + d];
        float asrc = a0[h * 2 * DH + d];
        float adst = a0[h * 2 * DH + DH + d];
        f16x8 wv[2];
#pragma unroll
        for (int n = 0; n < 16; ++n) {
            float wh = 0.f;
#pragma unroll
            for (int f = 0; f < FIN; ++f) wh = fmaf(xs[n * FIN + f], w0r[f], wh);
            wv[n >> 3][n & 7] = (_Float16)wh;
            float sv = wh * asrc, dv = wh * adst;
#pragma unroll
            for (int off = 1; off <= 32; off <<= 1) {
                sv += __shfl_xor(sv, off);
                dv += __shfl_xor(dv, off);
            }
            if (d == 0) { fs[h * NN + n0 + n] = sv; fd[h * NN + n0 + n] = dv; }
        }
        _Float16* dst = whT + ((size_t)(h * DH + d) * NN + n0);
        *(f16x8*)(dst) = wv[0];
        *(f16x8*)(dst + 8) = wv[1];
    } else {
        int u = (bid - 8448) * 256 + tid;
        int h = u >> 14, f = (u >> 6) & 255, d = u & 63;
        w1T[((size_t)(h * DH + d) << 8) + f] = (_Float16)W1[u];
    }
}

// ---- per-head max of fd (4 blocks, no atomics) ----
__global__ __launch_bounds__(256) void k_fdmax(const float* __restrict__ fd,
        float* __restrict__ fdm) {
    int h = blockIdx.x, tid = threadIdx.x;
    float m = -3e38f;
    for (int i = tid; i < NN; i += 256) m = fmaxf(m, fd[h * NN + i]);
#pragma unroll
    for (int off = 1; off <= 32; off <<= 1) m = fmaxf(m, __shfl_xor(m, off));
    __shared__ float mx[4];
    if ((tid & 63) == 0) mx[tid >> 6] = m;
    __syncthreads();
    if (tid == 0) fdm[h] = fmaxf(fmaxf(mx[0], mx[1]), fmaxf(mx[2], mx[3]));
}

// ---- separable-exp precompute: F=exp(fd-fdm), Fp=exp(a(fd-fdm)),
//      E=exp(su-m), Ep=exp(a*su-m), su=fs+fdm, m=max(su,a*su) ----
__global__ __launch_bounds__(256) void k_prep(const float* __restrict__ fs,
        const float* __restrict__ fd, const float* __restrict__ fdm,
        float* __restrict__ E, float* __restrict__ Ep,
        float* __restrict__ F, float* __restrict__ Fp) {
    int u = blockIdx.x * 256 + threadIdx.x;      // h*NN + n
    int h = u >> 12;
    float fm = fdm[h];
    float dv = fd[u] - fm;
    F[u]  = __expf(dv);
    Fp[u] = __expf(ALPHA * dv);
    float su = fs[u] + fm;
    float m = fmaxf(su, ALPHA * su);
    E[u]  = __expf(su - m);
    Ep[u] = __expf(ALPHA * su - m);
}

// ---- attention partial: counted-vmcnt flash pipeline + separable-exp max-trick.
// p_ij = adj_ij * max(E_i*F_j, Ep_i*Fp_j)  — NO transcendental in the inner loop.
// Block = 64 rows x 2048 cols, 8 waves = 2 row-groups x 4 col-quarters.
// 8 VMEM/phase (2 stage + 6 feeders), steady 16 in flight, wait vmcnt(8).
// Full-rank LDS swizzle: slot = ((cq<<2)|g) ^ rl on BOTH stage-src and read.
// writes pv[ch][h][n][64] f32 and pl[ch][h][n] f32
__global__ __launch_bounds__(512) void k_attn(const float* __restrict__ E,
        const float* __restrict__ Ep, const float* __restrict__ F,
        const float* __restrict__ Fp, const _Float16* __restrict__ whT,
        const unsigned char* __restrict__ bits,
        float* __restrict__ pv, float* __restrict__ pl) {
    __shared__ __align__(16) char smem[34304];  // 2x16KB stage; epilogue overlay
    const int ch = blockIdx.x & 1;
    const int rowblk = (blockIdx.x >> 1) & 63;
    const int h = blockIdx.x >> 7;
    const int row0 = rowblk << 6;               // 64 rows per block
    const int cb0 = ch << 11;                   // 2048-col half base
    const int tid = threadIdx.x;
    const int l = tid & 63, w = tid >> 6;       // 8 waves
    const int rl = l & 15, g = l >> 4;
    const int rg = w >> 2, cq = w & 3;          // row-group, col-quarter
    const int r0 = row0 + rg * 32 + rl;
    const int r1 = r0 + 16;
    const float E0  = E[h * NN + r0],  E1  = E[h * NN + r1];
    const float E0p = Ep[h * NN + r0], E1p = Ep[h * NN + r1];
    const float* Fq  = F  + h * NN + cb0 + cq * 32 + g * 8;
    const float* Fpq = Fp + h * NN + cb0 + cq * 32 + g * 8;
    const unsigned char* bp0 = bits + (size_t)r0 * (NN / 8) + (cb0 >> 3) + cq * 4;
    const unsigned char* bp1 = bits + (size_t)r1 * (NN / 8) + (cb0 >> 3) + cq * 4;
    const _Float16* whb = whT + (size_t)h * DH * NN + cb0;

    // stage source (pre-swizzled global addr, linear LDS dest); slot swz = d&15
    const int d0_ = tid >> 4, c0_ = tid & 15;
    const int d1_ = 32 + (tid >> 4), c1_ = tid & 15;
    const _Float16* src0 = whb + (size_t)d0_ * NN + 8 * (c0_ ^ (d0_ & 15));
    const _Float16* src1 = whb + (size_t)d1_ * NN + 8 * (c1_ ^ (d1_ & 15));

    f32x4 acc0[4] = {{0,0,0,0},{0,0,0,0},{0,0,0,0},{0,0,0,0}};
    f32x4 acc1[4] = {{0,0,0,0},{0,0,0,0},{0,0,0,0},{0,0,0,0}};
    f32x4 al0 = {0,0,0,0}, al1 = {0,0,0,0};
    f16x8 ones;
#pragma unroll
    for (int i = 0; i < 8; ++i) ones[i] = (_Float16)1.0f;
    const int rdswz = ((((cq << 2) | g) ^ rl) << 4);   // full-rank: 4 lanes/slot

    float4 faA, fbA, fpaA, fpbA, faB, fbB, fpaB, fpbB;
    unsigned int mA0, mA1, mB0, mB1;

#define STAGE(BOFF, T)                                                          \
    gload_lds16(src0 + (T) * 128, smem + (BOFF) + w * 1024);                    \
    gload_lds16(src1 + (T) * 128, smem + (BOFF) + 8192 + w * 1024);

#define FEED(FA, FB, FPA, FPB, M0v, M1v, T)                                     \
    FA  = *(const float4*)(Fq  + (T) * 128);                                    \
    FB  = *(const float4*)(Fq  + (T) * 128 + 4);                                \
    FPA = *(const float4*)(Fpq + (T) * 128);                                    \
    FPB = *(const float4*)(Fpq + (T) * 128 + 4);                                \
    M0v = *(const unsigned int*)(bp0 + (T) * 16);                               \
    M1v = *(const unsigned int*)(bp1 + (T) * 16);

#define COMPUTE(BOFF, FA, FB, FPA, FPB, M0v, M1v)                               \
    {                                                                           \
        const char* buf_ = smem + (BOFF);                                       \
        const float fv[8] = {FA.x, FA.y, FA.z, FA.w, FB.x, FB.y, FB.z, FB.w};   \
        const float fp[8] = {FPA.x, FPA.y, FPA.z, FPA.w, FPB.x, FPB.y, FPB.z, FPB.w}; \
        f16x8 av0, av1;                                                         \
        const int sh = g << 3;                                                  \
        _Pragma("unroll")                                                       \
        for (int i = 0; i < 8; i += 2) {                                        \
            float ta = fmaxf(E0 * fv[i], E0p * fp[i]);                          \
            ta = ((M0v >> (sh + i)) & 1u) ? ta : 0.f;                           \
            float tb = fmaxf(E0 * fv[i+1], E0p * fp[i+1]);                      \
            tb = ((M0v >> (sh + i + 1)) & 1u) ? tb : 0.f;                       \
            fp16x2 p0 = __builtin_amdgcn_cvt_pkrtz(ta, tb);                     \
            av0[i] = (_Float16)p0[0]; av0[i+1] = (_Float16)p0[1];               \
            float tc = fmaxf(E1 * fv[i], E1p * fp[i]);                          \
            tc = ((M1v >> (sh + i)) & 1u) ? tc : 0.f;                           \
            float td = fmaxf(E1 * fv[i+1], E1p * fp[i+1]);                      \
            td = ((M1v >> (sh + i + 1)) & 1u) ? td : 0.f;                       \
            fp16x2 p1 = __builtin_amdgcn_cvt_pkrtz(tc, td);                     \
            av1[i] = (_Float16)p1[0]; av1[i+1] = (_Float16)p1[1];               \
        }                                                                       \
        al0 = __builtin_amdgcn_mfma_f32_16x16x32_f16(av0, ones, al0, 0, 0, 0);  \
        al1 = __builtin_amdgcn_mfma_f32_16x16x32_f16(av1, ones, al1, 0, 0, 0);  \
        _Pragma("unroll")                                                       \
        for (int t4 = 0; t4 < 4; ++t4) {                                        \
            f16x8 bv = *(const f16x8*)(buf_ + ((16 * t4 + rl) << 8) + rdswz);   \
            acc0[t4] = __builtin_amdgcn_mfma_f32_16x16x32_f16(av0, bv, acc0[t4], 0, 0, 0); \
            acc1[t4] = __builtin_amdgcn_mfma_f32_16x16x32_f16(av1, bv, acc1[t4], 0, 0, 0); \
        }                                                                       \
    }

#define WAIT8 asm volatile("s_waitcnt vmcnt(8)" ::: "memory");                  \
    __builtin_amdgcn_s_barrier();                                               \
    __builtin_amdgcn_sched_barrier(0);

    // prologue: 2 phase-groups of 8 loads -> 16 in flight
    STAGE(0, 0);      FEED(faA, fbA, fpaA, fpbA, mA0, mA1, 0);
    STAGE(16384, 1);  FEED(faB, fbB, fpaB, fpbB, mB0, mB1, 1);

#pragma unroll 1
    for (int k = 0; k < 7; ++k) {
        WAIT8                                    // group(2k) landed
        COMPUTE(0, faA, fbA, fpaA, fpbA, mA0, mA1);
        __builtin_amdgcn_s_barrier();            // all waves done reading buf0
        STAGE(0, 2 * k + 2);  FEED(faA, fbA, fpaA, fpbA, mA0, mA1, 2 * k + 2);
        WAIT8                                    // group(2k+1) landed
        COMPUTE(16384, faB, fbB, fpaB, fpbB, mB0, mB1);
        __builtin_amdgcn_s_barrier();            // all waves done reading buf1
        STAGE(16384, 2 * k + 3);  FEED(faB, fbB, fpaB, fpbB, mB0, mB1, 2 * k + 3);
    }
    // peeled tail: tiles 14, 15
    WAIT8
    COMPUTE(0, faA, fbA, fpaA, fpbA, mA0, mA1);
    asm volatile("s_waitcnt vmcnt(0)" ::: "memory");
    __builtin_amdgcn_s_barrier();
    __builtin_amdgcn_sched_barrier(0);
    COMPUTE(16384, faB, fbB, fpaB, fpbB, mB0, mB1);
    __syncthreads();
#undef WAIT8
#undef COMPUTE
#undef FEED
#undef STAGE

    // ---- epilogue: stride-66 staging, 4-way cq reduce ----
    float* red = (float*)smem;                   // [4 cq][32 rows][66]
    float* lred = (float*)(smem + 33792);        // [4 cq][32 rows]
#pragma unroll
    for (int p = 0; p < 2; ++p) {
        if (rg == p) {
#pragma unroll
            for (int t4 = 0; t4 < 4; ++t4)
#pragma unroll
                for (int i = 0; i < 4; ++i) {
                    red[(cq * 32 + 4 * g + i) * 66 + 16 * t4 + rl]      = acc0[t4][i];
                    red[(cq * 32 + 16 + 4 * g + i) * 66 + 16 * t4 + rl] = acc1[t4][i];
                }
            if (rl == 0) {
#pragma unroll
                for (int i = 0; i < 4; ++i) {
                    lred[cq * 32 + 4 * g + i]      = al0[i];
                    lred[cq * 32 + 16 + 4 * g + i] = al1[i];
                }
            }
        }
        __syncthreads();
#pragma unroll
        for (int j = 0; j < 4; ++j) {
            const int R = w * 4 + j;
            float v = 0.f, L = 0.f;
#pragma unroll
            for (int cc = 0; cc < 4; ++cc) {
                v += red[(cc * 32 + R) * 66 + l];
                L += lred[cc * 32 + R];
            }
            const int Rg = row0 + p * 32 + R;
            pv[(((size_t)(ch * NH + h) * NN) + Rg) * 64 + l] = v;
            if (l == 0) pl[(size_t)(ch * NH + h) * NN + Rg] = L;
        }
        __syncthreads();
    }
}

// ---- merge halves; MODE 0 -> h16 [n][H*DH] f16 ; MODE 1 -> head-mean out f32 ----
template<int MODE>
__global__ __launch_bounds__(256) void k_merge(const float* __restrict__ pv,
        const float* __restrict__ pl, void* __restrict__ outp) {
    int t = blockIdx.x * 256 + threadIdx.x;
    if (MODE == 0) {
        int d = t & 63, n = (t >> 6) & (NN - 1), h = t >> 18;
        float v = pv[((size_t)h * NN + n) * 64 + d] + pv[((size_t)(NH + h) * NN + n) * 64 + d];
        float L = pl[h * NN + n] + pl[NH * NN + h * NN + n];
        float o = v * __builtin_amdgcn_rcpf(L);
        o = o > 0.f ? o : __expf(o) - 1.f;
        ((_Float16*)outp)[(size_t)n * (NH * DH) + h * DH + d] = (_Float16)o;
    } else {
        int d = t & 63, n = t >> 6;
        float s = 0.f;
#pragma unroll
        for (int h = 0; h < NH; ++h) {
            float v = pv[((size_t)h * NN + n) * 64 + d] + pv[((size_t)(NH + h) * NN + n) * 64 + d];
            float L = pl[h * NN + n] + pl[NH * NN + h * NN + n];
            float o = v * __builtin_amdgcn_rcpf(L);
            s += o > 0.f ? o : __expf(o) - 1.f;
        }
        ((float*)outp)[t] = 0.25f * s;
    }
}

// ---- layer1 Wh via MFMA + fs/fd (no atomics); writes whT1 ----
__global__ __launch_bounds__(256) void k_l1wh(const _Float16* __restrict__ h16,
        const _Float16* __restrict__ w1T, const float* __restrict__ a1,
        _Float16* __restrict__ whT, float* __restrict__ fs, float* __restrict__ fd) {
    __shared__ float red[4][16][64];
    __shared__ _Float16 lt[16][64];
    int h = blockIdx.x >> 8;
    int row0 = (blockIdx.x & 255) << 4;
    int tid = threadIdx.x;
    int l = tid & 63, w = tid >> 6;
    int rl = l & 15, g = l >> 4;
    f32x4 acc[4] = {{0,0,0,0},{0,0,0,0},{0,0,0,0},{0,0,0,0}};
    const _Float16* ap = h16 + (size_t)(row0 + rl) * (NH * DH) + w * 64;
    const _Float16* bp = w1T + ((size_t)h * DH << 8) + w * 64;
#pragma unroll
    for (int j = 0; j < 2; ++j) {
        int fb = j * 32 + 8 * g;
        f16x8 avv = *(const f16x8*)(ap + fb);
#pragma unroll
        for (int t4 = 0; t4 < 4; ++t4) {
            f16x8 bv = *(const f16x8*)(bp + ((size_t)(16 * t4 + rl) << 8) + fb);
            acc[t4] = __builtin_amdgcn_mfma_f32_16x16x32_f16(avv, bv, acc[t4], 0, 0, 0);
        }
    }
#pragma unroll
    for (int t4 = 0; t4 < 4; ++t4)
#pragma unroll
        for (int i = 0; i < 4; ++i) red[w][t4 * 4 + i][l] = acc[t4][i];
    __syncthreads();
#pragma unroll
    for (int i = 0; i < 4; ++i) {
        float v = red[0][w * 4 + i][l] + red[1][w * 4 + i][l]
                + red[2][w * 4 + i][l] + red[3][w * 4 + i][l];
        lt[4 * g + i][16 * w + rl] = (_Float16)v;
    }
    __syncthreads();
    int d = tid & 63, rb = tid >> 6;
    f16x4 o;
#pragma unroll
    for (int j = 0; j < 4; ++j) o[j] = lt[rb * 4 + j][d];
    *(f16x4*)(whT + (size_t)(h * DH + d) * NN + row0 + rb * 4) = o;
    float as_ = a1[h * 2 * DH + d], ad_ = a1[h * 2 * DH + DH + d];
    float svj[4], dvj[4];
#pragma unroll
    for (int j = 0; j < 4; ++j) {
        float wv = (float)lt[rb * 4 + j][d];
        svj[j] = wv * as_;
        dvj[j] = wv * ad_;
    }
#pragma unroll
    for (int off = 1; off <= 32; off <<= 1) {
#pragma unroll
        for (int j = 0; j < 4; ++j) {
            svj[j] += __shfl_xor(svj[j], off);
            dvj[j] += __shfl_xor(dvj[j], off);
        }
    }
    if (d == 0) {
#pragma unroll
        for (int j = 0; j < 4; ++j) {
            fs[h * NN + row0 + rb * 4 + j] = svj[j];
            fd[h * NN + row0 + rb * 4 + j] = dvj[j];
        }
    }
}

extern "C" void kernel_launch(void* const* d_in, const int* in_sizes, int n_in,
                              void* d_out, int out_size, void* d_ws, size_t ws_size,
                              hipStream_t stream) {
    const float* x  = (const float*)d_in[0];
    const int* adj  = (const int*)d_in[1];
    const float* W0 = (const float*)d_in[2];
    const float* a0 = (const float*)d_in[3];
    const float* W1 = (const float*)d_in[4];
    const float* a1 = (const float*)d_in[5];
    float* out = (float*)d_out;
    char* ws = (char*)d_ws;

    unsigned char* bits = (unsigned char*)(ws);                        // 2MB
    _Float16* whT0 = (_Float16*)(ws + (2ull << 20));                   // 2MB
    _Float16* h16  = (_Float16*)(ws + (4ull << 20));                   // 2MB
    _Float16* w1T  = (_Float16*)(ws + (6ull << 20));                   // 128KB
    _Float16* whT1 = (_Float16*)(ws + (6ull << 20) + (256ull << 10));  // 2MB
    float* fs0  = (float*)(ws + (9ull << 20));
    float* fd0  = fs0 + NH * NN;
    float* fs1  = fd0 + NH * NN;
    float* fd1  = fs1 + NH * NN;
    float* fdm0 = fd1 + NH * NN;   // 8 floats
    float* fdm1 = fdm0 + 8;
    float* pv   = (float*)(ws + (10ull << 20));                        // 8MB
    float* pl   = (float*)(ws + (18ull << 20));                        // 128KB
    float* Ea   = (float*)(ws + (19ull << 20));                        // 64KB
    float* Epa  = Ea + NH * NN;
    float* Fa   = Epa + NH * NN;
    float* Fpa  = Fa + NH * NN;

    k_front<<<8704, 256, 0, stream>>>(adj, bits, x, W0, a0, whT0, fs0, fd0, W1, w1T);
    k_fdmax<<<NH, 256, 0, stream>>>(fd0, fdm0);
    k_prep<<<NH * NN / 256, 256, 0, stream>>>(fs0, fd0, fdm0, Ea, Epa, Fa, Fpa);
    k_attn<<<2 * NH * (NN / 64), 512, 0, stream>>>(Ea, Epa, Fa, Fpa, whT0, bits, pv, pl);
    k_merge<0><<<(NH * NN * DH) / 256, 256, 0, stream>>>(pv, pl, h16);
    k_l1wh<<<NH * (NN / 16), 256, 0, stream>>>(h16, w1T, a1, whT1, fs1, fd1);
    k_fdmax<<<NH, 256, 0, stream>>>(fd1, fdm1);
    k_prep<<<NH * NN / 256, 256, 0, stream>>>(fs1, fd1, fdm1, Ea, Epa, Fa, Fpa);
    k_attn<<<2 * NH * (NN / 64), 512, 0, stream>>>(Ea, Epa, Fa, Fpa, whT1, bits, pv, pl);
    k_merge<1><<<(NN * DH) / 256, 256, 0, stream>>>(pv, pl, out);
}

// Round 14
// 140.666 us; speedup vs baseline: 1.0804x; 1.0804x over previous
//
#include <hip/hip_runtime.h>
#include <hip/hip_fp16.h>
#include <math.h>

#define NN 4096
#define FIN 20
#define NH 4
#define DH 64
#define ALPHA 0.2f
#define LOG2E 1.4426950408889634f

typedef _Float16 f16x8 __attribute__((ext_vector_type(8)));
typedef _Float16 f16x4 __attribute__((ext_vector_type(4)));
typedef __fp16 fp16x2 __attribute__((ext_vector_type(2)));
typedef float f32x4 __attribute__((ext_vector_type(4)));

__device__ inline void gload_lds16(const void* gsrc, void* ldsbase) {
    __builtin_amdgcn_global_load_lds(
        (const __attribute__((address_space(1))) void*)gsrc,
        (__attribute__((address_space(3))) void*)ldsbase, 16, 0, 0);
}

// ---- fused front kernel: pack (blocks 0..8191) | l0wh (8192..8447) | w1t (8448..8703)
__global__ __launch_bounds__(256) void k_front(const int* __restrict__ adj,
        unsigned char* __restrict__ bits, const float* __restrict__ x,
        const float* __restrict__ W0, const float* __restrict__ a0,
        _Float16* __restrict__ whT, float* __restrict__ fs, float* __restrict__ fd,
        const float* __restrict__ W1, _Float16* __restrict__ w1T) {
    __shared__ float xs[16 * FIN];
    const int bid = blockIdx.x;
    const int tid = threadIdx.x;
    if (bid < 8192) {
        int t = bid * 256 + tid;
        const int4* p = (const int4*)(adj + (size_t)t * 8);
        int4 a = p[0], b = p[1];
        unsigned int byte = 0;
        byte |= (a.x > 0) << 0; byte |= (a.y > 0) << 1;
        byte |= (a.z > 0) << 2; byte |= (a.w > 0) << 3;
        byte |= (b.x > 0) << 4; byte |= (b.y > 0) << 5;
        byte |= (b.z > 0) << 6; byte |= (b.w > 0) << 7;
        bits[t] = (unsigned char)byte;
    } else if (bid < 8448) {
        int n0 = (bid - 8192) * 16;
        for (int i = tid; i < 16 * FIN; i += 256) xs[i] = x[n0 * FIN + i];
        __syncthreads();
        int h = tid >> 6, d = tid & 63;
        float w0r[FIN];
#pragma unroll
        for (int f = 0; f < FIN; ++f) w0r[f] = W0[(h * FIN + f) * DH + d];
        float asrc = a0[h * 2 * DH + d];
        float adst = a0[h * 2 * DH + DH + d];
        f16x8 wv[2];
#pragma unroll
        for (int n = 0; n < 16; ++n) {
            float wh = 0.f;
#pragma unroll
            for (int f = 0; f < FIN; ++f) wh = fmaf(xs[n * FIN + f], w0r[f], wh);
            wv[n >> 3][n & 7] = (_Float16)wh;
            float sv = wh * asrc, dv = wh * adst;
#pragma unroll
            for (int off = 1; off <= 32; off <<= 1) {
                sv += __shfl_xor(sv, off);
                dv += __shfl_xor(dv, off);
            }
            if (d == 0) { fs[h * NN + n0 + n] = sv; fd[h * NN + n0 + n] = dv; }
        }
        _Float16* dst = whT + ((size_t)(h * DH + d) * NN + n0);
        *(f16x8*)(dst) = wv[0];
        *(f16x8*)(dst + 8) = wv[1];
    } else {
        int u = (bid - 8448) * 256 + tid;
        int h = u >> 14, f = (u >> 6) & 255, d = u & 63;
        w1T[((size_t)(h * DH + d) << 8) + f] = (_Float16)W1[u];
    }
}

// ---- per-head max of fd (4 blocks, no atomics) ----
__global__ __launch_bounds__(256) void k_fdmax(const float* __restrict__ fd,
        float* __restrict__ fdm) {
    int h = blockIdx.x, tid = threadIdx.x;
    float m = -3e38f;
    for (int i = tid; i < NN; i += 256) m = fmaxf(m, fd[h * NN + i]);
#pragma unroll
    for (int off = 1; off <= 32; off <<= 1) m = fmaxf(m, __shfl_xor(m, off));
    __shared__ float mx[4];
    if ((tid & 63) == 0) mx[tid >> 6] = m;
    __syncthreads();
    if (tid == 0) fdm[h] = fmaxf(fmaxf(mx[0], mx[1]), fmaxf(mx[2], mx[3]));
}

// ---- attention partial: counted-vmcnt flash pipeline, 32-row blocks for 2x grid.
// Block = 32 rows x 2048 cols, 8 waves = 4 col-quarters x 2 row-groups (16 rows).
// Single acc set per wave -> target VGPR <= 64 (occupancy cliff; R12/R13 lesson).
// 5 VMEM/phase (2 stage + 2 fd + 1 mask), steady 10 in flight, wait vmcnt(5).
// Full-rank LDS swizzle (R13): slot = ((cq<<2)|g) ^ rl on stage-src and read.
// writes pv[ch][h][n][64] f32 and pl[ch][h][n] f32
__global__ __launch_bounds__(512) void k_attn(const float* __restrict__ fs,
        const float* __restrict__ fd, const float* __restrict__ fdmax,
        const _Float16* __restrict__ whT, const unsigned char* __restrict__ bits,
        float* __restrict__ pv, float* __restrict__ pl) {
    __shared__ __align__(16) char smem[34304];  // 2x16KB stage; epilogue overlay
    const int ch = blockIdx.x & 1;
    const int rowblk = (blockIdx.x >> 1) & 127;
    const int h = blockIdx.x >> 8;
    const int row0 = rowblk << 5;               // 32 rows per block
    const int cb0 = ch << 11;                   // 2048-col half base
    const int tid = threadIdx.x;
    const int l = tid & 63, w = tid >> 6;       // 8 waves
    const int rl = l & 15, g = l >> 4;
    const int cq = w & 3, rg = w >> 2;          // col-quarter, row-group
    const int r0 = row0 + rg * 16 + rl;
    const float fsr = fs[h * NN + r0];
    const float fm = fdmax[h];
    const float su = fsr + fm;
    const float m0 = fmaxf(su, ALPHA * su);     // upper bound of row max
    const float A0 = (fsr - m0) * LOG2E, B0 = (ALPHA * fsr - m0) * LOG2E;
    const float* fdp = fd + h * NN + cb0 + cq * 32 + g * 8;
    const unsigned char* bp0 = bits + (size_t)r0 * (NN / 8) + (cb0 >> 3) + cq * 4;
    const _Float16* whb = whT + (size_t)h * DH * NN + cb0;

    // stage source (pre-swizzled global addr, linear LDS dest); full-rank swz
    const int d0_ = tid >> 4, c0_ = tid & 15;
    const int d1_ = 32 + (tid >> 4), c1_ = tid & 15;
    const _Float16* src0 = whb + (size_t)d0_ * NN + 8 * (c0_ ^ (d0_ & 15));
    const _Float16* src1 = whb + (size_t)d1_ * NN + 8 * (c1_ ^ (d1_ & 15));

    f32x4 acc[4] = {{0,0,0,0},{0,0,0,0},{0,0,0,0},{0,0,0,0}};
    f32x4 al = {0,0,0,0};
    f16x8 ones;
#pragma unroll
    for (int i = 0; i < 8; ++i) ones[i] = (_Float16)1.0f;
    const int rdswz = ((((cq << 2) | g) ^ rl) << 4);   // 4 lanes/slot uniform

    float4 faA, fbA, faB, fbB;
    unsigned int mA0, mB0;

#define STAGE(BOFF, T)                                                          \
    gload_lds16(src0 + (T) * 128, smem + (BOFF) + w * 1024);                    \
    gload_lds16(src1 + (T) * 128, smem + (BOFF) + 8192 + w * 1024);

#define FEED(FA, FB, M0v, T)                                                    \
    FA = *(const float4*)(fdp + (T) * 128);                                     \
    FB = *(const float4*)(fdp + (T) * 128 + 4);                                 \
    M0v = *(const unsigned int*)(bp0 + (T) * 16);

#define COMPUTE(BOFF, FA, FB, M0v)                                              \
    {                                                                           \
        const char* buf_ = smem + (BOFF);                                       \
        const float fv[8] = {FA.x, FA.y, FA.z, FA.w, FB.x, FB.y, FB.z, FB.w};   \
        f16x8 av;                                                               \
        const int sh = g << 3;                                                  \
        _Pragma("unroll")                                                       \
        for (int i = 0; i < 8; i += 2) {                                        \
            float ta = fmaxf(fmaf(fv[i], LOG2E, A0), fmaf(fv[i], ALPHA * LOG2E, B0)); \
            ta = ((M0v >> (sh + i)) & 1u) ? ta : -1e30f;                        \
            float tb = fmaxf(fmaf(fv[i+1], LOG2E, A0), fmaf(fv[i+1], ALPHA * LOG2E, B0)); \
            tb = ((M0v >> (sh + i + 1)) & 1u) ? tb : -1e30f;                    \
            fp16x2 p0 = __builtin_amdgcn_cvt_pkrtz(exp2f(ta), exp2f(tb));       \
            av[i] = (_Float16)p0[0]; av[i+1] = (_Float16)p0[1];                 \
        }                                                                       \
        al = __builtin_amdgcn_mfma_f32_16x16x32_f16(av, ones, al, 0, 0, 0);     \
        _Pragma("unroll")                                                       \
        for (int t4 = 0; t4 < 4; ++t4) {                                        \
            f16x8 bv = *(const f16x8*)(buf_ + ((16 * t4 + rl) << 8) + rdswz);   \
            acc[t4] = __builtin_amdgcn_mfma_f32_16x16x32_f16(av, bv, acc[t4], 0, 0, 0); \
        }                                                                       \
    }

#define WAIT5 asm volatile("s_waitcnt vmcnt(5)" ::: "memory");                  \
    __builtin_amdgcn_s_barrier();                                               \
    __builtin_amdgcn_sched_barrier(0);

    // prologue: 2 phase-groups of 5 loads -> 10 in flight
    STAGE(0, 0);      FEED(faA, fbA, mA0, 0);
    STAGE(16384, 1);  FEED(faB, fbB, mB0, 1);

#pragma unroll 1
    for (int k = 0; k < 7; ++k) {
        WAIT5                                    // group(2k) landed
        COMPUTE(0, faA, fbA, mA0);
        __builtin_amdgcn_s_barrier();            // all waves done reading buf0
        STAGE(0, 2 * k + 2);  FEED(faA, fbA, mA0, 2 * k + 2);
        WAIT5                                    // group(2k+1) landed
        COMPUTE(16384, faB, fbB, mB0);
        __builtin_amdgcn_s_barrier();            // all waves done reading buf1
        STAGE(16384, 2 * k + 3);  FEED(faB, fbB, mB0, 2 * k + 3);
    }
    // peeled tail: tiles 14, 15
    WAIT5
    COMPUTE(0, faA, fbA, mA0);
    asm volatile("s_waitcnt vmcnt(0)" ::: "memory");
    __builtin_amdgcn_s_barrier();
    __builtin_amdgcn_sched_barrier(0);
    COMPUTE(16384, faB, fbB, mB0);
    __syncthreads();
#undef WAIT5
#undef COMPUTE
#undef FEED
#undef STAGE

    // ---- epilogue: single pass, stride-66 staging, 4-way cq reduce ----
    float* red = (float*)smem;                   // [4 cq][32 rows][66]
    float* lred = (float*)(smem + 33792);        // [4 cq][32 rows]
#pragma unroll
    for (int t4 = 0; t4 < 4; ++t4)
#pragma unroll
        for (int i = 0; i < 4; ++i)
            red[(cq * 32 + rg * 16 + 4 * g + i) * 66 + 16 * t4 + rl] = acc[t4][i];
    if (rl == 0) {
#pragma unroll
        for (int i = 0; i < 4; ++i)
            lred[cq * 32 + rg * 16 + 4 * g + i] = al[i];
    }
    __syncthreads();
#pragma unroll
    for (int j = 0; j < 4; ++j) {
        const int R = w * 4 + j;                 // 8 waves x 4 = 32 rows
        float v = 0.f, L = 0.f;
#pragma unroll
        for (int cc = 0; cc < 4; ++cc) {
            v += red[(cc * 32 + R) * 66 + l];
            L += lred[cc * 32 + R];
        }
        const int Rg = row0 + R;
        pv[(((size_t)(ch * NH + h) * NN) + Rg) * 64 + l] = v;
        if (l == 0) pl[(size_t)(ch * NH + h) * NN + Rg] = L;
    }
}

// ---- merge halves; MODE 0 -> h16 [n][H*DH] f16 ; MODE 1 -> head-mean out f32 ----
template<int MODE>
__global__ __launch_bounds__(256) void k_merge(const float* __restrict__ pv,
        const float* __restrict__ pl, void* __restrict__ outp) {
    int t = blockIdx.x * 256 + threadIdx.x;
    if (MODE == 0) {
        int d = t & 63, n = (t >> 6) & (NN - 1), h = t >> 18;
        float v = pv[((size_t)h * NN + n) * 64 + d] + pv[((size_t)(NH + h) * NN + n) * 64 + d];
        float L = pl[h * NN + n] + pl[NH * NN + h * NN + n];
        float o = v * __builtin_amdgcn_rcpf(L);
        o = o > 0.f ? o : __expf(o) - 1.f;
        ((_Float16*)outp)[(size_t)n * (NH * DH) + h * DH + d] = (_Float16)o;
    } else {
        int d = t & 63, n = t >> 6;
        float s = 0.f;
#pragma unroll
        for (int h = 0; h < NH; ++h) {
            float v = pv[((size_t)h * NN + n) * 64 + d] + pv[((size_t)(NH + h) * NN + n) * 64 + d];
            float L = pl[h * NN + n] + pl[NH * NN + h * NN + n];
            float o = v * __builtin_amdgcn_rcpf(L);
            s += o > 0.f ? o : __expf(o) - 1.f;
        }
        ((float*)outp)[t] = 0.25f * s;
    }
}

// ---- layer1 Wh via MFMA + fs/fd (no atomics); writes whT1 ----
__global__ __launch_bounds__(256) void k_l1wh(const _Float16* __restrict__ h16,
        const _Float16* __restrict__ w1T, const float* __restrict__ a1,
        _Float16* __restrict__ whT, float* __restrict__ fs, float* __restrict__ fd) {
    __shared__ float red[4][16][64];
    __shared__ _Float16 lt[16][64];
    int h = blockIdx.x >> 8;
    int row0 = (blockIdx.x & 255) << 4;
    int tid = threadIdx.x;
    int l = tid & 63, w = tid >> 6;
    int rl = l & 15, g = l >> 4;
    f32x4 acc[4] = {{0,0,0,0},{0,0,0,0},{0,0,0,0},{0,0,0,0}};
    const _Float16* ap = h16 + (size_t)(row0 + rl) * (NH * DH) + w * 64;
    const _Float16* bp = w1T + ((size_t)h * DH << 8) + w * 64;
#pragma unroll
    for (int j = 0; j < 2; ++j) {
        int fb = j * 32 + 8 * g;
        f16x8 avv = *(const f16x8*)(ap + fb);
#pragma unroll
        for (int t4 = 0; t4 < 4; ++t4) {
            f16x8 bv = *(const f16x8*)(bp + ((size_t)(16 * t4 + rl) << 8) + fb);
            acc[t4] = __builtin_amdgcn_mfma_f32_16x16x32_f16(avv, bv, acc[t4], 0, 0, 0);
        }
    }
#pragma unroll
    for (int t4 = 0; t4 < 4; ++t4)
#pragma unroll
        for (int i = 0; i < 4; ++i) red[w][t4 * 4 + i][l] = acc[t4][i];
    __syncthreads();
#pragma unroll
    for (int i = 0; i < 4; ++i) {
        float v = red[0][w * 4 + i][l] + red[1][w * 4 + i][l]
                + red[2][w * 4 + i][l] + red[3][w * 4 + i][l];
        lt[4 * g + i][16 * w + rl] = (_Float16)v;
    }
    __syncthreads();
    int d = tid & 63, rb = tid >> 6;
    f16x4 o;
#pragma unroll
    for (int j = 0; j < 4; ++j) o[j] = lt[rb * 4 + j][d];
    *(f16x4*)(whT + (size_t)(h * DH + d) * NN + row0 + rb * 4) = o;
    float as_ = a1[h * 2 * DH + d], ad_ = a1[h * 2 * DH + DH + d];
    float svj[4], dvj[4];
#pragma unroll
    for (int j = 0; j < 4; ++j) {
        float wv = (float)lt[rb * 4 + j][d];
        svj[j] = wv * as_;
        dvj[j] = wv * ad_;
    }
#pragma unroll
    for (int off = 1; off <= 32; off <<= 1) {
#pragma unroll
        for (int j = 0; j < 4; ++j) {
            svj[j] += __shfl_xor(svj[j], off);
            dvj[j] += __shfl_xor(dvj[j], off);
        }
    }
    if (d == 0) {
#pragma unroll
        for (int j = 0; j < 4; ++j) {
            fs[h * NN + row0 + rb * 4 + j] = svj[j];
            fd[h * NN + row0 + rb * 4 + j] = dvj[j];
        }
    }
}

extern "C" void kernel_launch(void* const* d_in, const int* in_sizes, int n_in,
                              void* d_out, int out_size, void* d_ws, size_t ws_size,
                              hipStream_t stream) {
    const float* x  = (const float*)d_in[0];
    const int* adj  = (const int*)d_in[1];
    const float* W0 = (const float*)d_in[2];
    const float* a0 = (const float*)d_in[3];
    const float* W1 = (const float*)d_in[4];
    const float* a1 = (const float*)d_in[5];
    float* out = (float*)d_out;
    char* ws = (char*)d_ws;

    unsigned char* bits = (unsigned char*)(ws);                        // 2MB
    _Float16* whT0 = (_Float16*)(ws + (2ull << 20));                   // 2MB
    _Float16* h16  = (_Float16*)(ws + (4ull << 20));                   // 2MB
    _Float16* w1T  = (_Float16*)(ws + (6ull << 20));                   // 128KB
    _Float16* whT1 = (_Float16*)(ws + (6ull << 20) + (256ull << 10));  // 2MB
    float* fs0  = (float*)(ws + (9ull << 20));
    float* fd0  = fs0 + NH * NN;
    float* fs1  = fd0 + NH * NN;
    float* fd1  = fs1 + NH * NN;
    float* fdm0 = fd1 + NH * NN;   // 8 floats
    float* fdm1 = fdm0 + 8;
    float* pv   = (float*)(ws + (10ull << 20));                        // 8MB
    float* pl   = (float*)(ws + (18ull << 20));                        // 128KB

    k_front<<<8704, 256, 0, stream>>>(adj, bits, x, W0, a0, whT0, fs0, fd0, W1, w1T);
    k_fdmax<<<NH, 256, 0, stream>>>(fd0, fdm0);
    k_attn<<<2 * NH * (NN / 32), 512, 0, stream>>>(fs0, fd0, fdm0, whT0, bits, pv, pl);
    k_merge<0><<<(NH * NN * DH) / 256, 256, 0, stream>>>(pv, pl, h16);
    k_l1wh<<<NH * (NN / 16), 256, 0, stream>>>(h16, w1T, a1, whT1, fs1, fd1);
    k_fdmax<<<NH, 256, 0, stream>>>(fd1, fdm1);
    k_attn<<<2 * NH * (NN / 32), 512, 0, stream>>>(fs1, fd1, fdm1, whT1, bits, pv, pl);
    k_merge<1><<<(NN * DH) / 256, 256, 0, stream>>>(pv, pl, out);
}

// Round 17
// 110.570 us; speedup vs baseline: 1.3745x; 1.2722x over previous
//
#include <hip/hip_runtime.h>
#include <hip/hip_fp16.h>
#include <math.h>

#define NN 4096
#define FIN 20
#define NH 4
#define DH 64
#define ALPHA 0.2f
#define LOG2E 1.4426950408889634f

typedef _Float16 f16x8 __attribute__((ext_vector_type(8)));
typedef _Float16 f16x4 __attribute__((ext_vector_type(4)));
typedef __fp16 fp16x2 __attribute__((ext_vector_type(2)));
typedef float f32x4 __attribute__((ext_vector_type(4)));

#if defined(__has_builtin)
#if __has_builtin(__builtin_amdgcn_exp2f)
#define FEXP2(x) __builtin_amdgcn_exp2f(x)
#endif
#endif
#ifndef FEXP2
extern "C" __device__ float __ocml_native_exp2_f32(float);
#define FEXP2(x) __ocml_native_exp2_f32(x)
#endif

__device__ inline void gload_lds16(const void* gsrc, void* ldsbase) {
    __builtin_amdgcn_global_load_lds(
        (const __attribute__((address_space(1))) void*)gsrc,
        (__attribute__((address_space(3))) void*)ldsbase, 16, 0, 0);
}

// ---- pack adjacency into bitmask (8 ints -> 1 byte per thread) ----
__global__ __launch_bounds__(256) void k_pack(const int* __restrict__ adj,
        unsigned char* __restrict__ bits) {
    int t = blockIdx.x * 256 + threadIdx.x;
    const int4* p = (const int4*)(adj + (size_t)t * 8);
    int4 a = p[0], b = p[1];
    unsigned int byte = 0;
    byte |= (a.x > 0) << 0; byte |= (a.y > 0) << 1;
    byte |= (a.z > 0) << 2; byte |= (a.w > 0) << 3;
    byte |= (b.x > 0) << 4; byte |= (b.y > 0) << 5;
    byte |= (b.z > 0) << 6; byte |= (b.w > 0) << 7;
    bits[t] = (unsigned char)byte;
}

// ---- layer0 Wh -> whT (f16, [h][d][n]) + fs/fd (no atomics) ----
__global__ __launch_bounds__(256) void k_l0wh(const float* __restrict__ x,
        const float* __restrict__ W0, const float* __restrict__ a0,
        _Float16* __restrict__ whT, float* __restrict__ fs, float* __restrict__ fd) {
    __shared__ float xs[16 * FIN];
    int n0 = blockIdx.x * 16;
    int tid = threadIdx.x;
    for (int i = tid; i < 16 * FIN; i += 256) xs[i] = x[n0 * FIN + i];
    __syncthreads();
    int h = tid >> 6, d = tid & 63;
    float w0r[FIN];
#pragma unroll
    for (int f = 0; f < FIN; ++f) w0r[f] = W0[(h * FIN + f) * DH + d];
    float asrc = a0[h * 2 * DH + d];
    float adst = a0[h * 2 * DH + DH + d];
    f16x8 wv[2];
#pragma unroll
    for (int n = 0; n < 16; ++n) {
        float wh = 0.f;
#pragma unroll
        for (int f = 0; f < FIN; ++f) wh = fmaf(xs[n * FIN + f], w0r[f], wh);
        wv[n >> 3][n & 7] = (_Float16)wh;
        float sv = wh * asrc, dv = wh * adst;
#pragma unroll
        for (int off = 1; off <= 32; off <<= 1) {
            sv += __shfl_xor(sv, off);
            dv += __shfl_xor(dv, off);
        }
        if (d == 0) { fs[h * NN + n0 + n] = sv; fd[h * NN + n0 + n] = dv; }
    }
    _Float16* dst = whT + ((size_t)(h * DH + d) * NN + n0);
    *(f16x8*)(dst) = wv[0];
    *(f16x8*)(dst + 8) = wv[1];
}

// ---- per-head max of fd (4 blocks, no atomics) ----
__global__ __launch_bounds__(256) void k_fdmax(const float* __restrict__ fd,
        float* __restrict__ fdm) {
    int h = blockIdx.x, tid = threadIdx.x;
    float m = -3e38f;
    for (int i = tid; i < NN; i += 256) m = fmaxf(m, fd[h * NN + i]);
#pragma unroll
    for (int off = 1; off <= 32; off <<= 1) m = fmaxf(m, __shfl_xor(m, off));
    __shared__ float mx[4];
    if ((tid & 63) == 0) mx[tid >> 6] = m;
    __syncthreads();
    if (tid == 0) fdm[h] = fmaxf(fmaxf(mx[0], mx[1]), fmaxf(mx[2], mx[3]));
}

// ---- W1 [h][256][64] -> w1T [h][64][256] f16 (read-coalesced) ----
__global__ void k_w1t(const float* __restrict__ W1, _Float16* __restrict__ w1T) {
    int u = blockIdx.x * 256 + threadIdx.x;     // 0..65535
    int h = u >> 14, f = (u >> 6) & 255, d = u & 63;
    w1T[((size_t)(h * DH + d) << 8) + f] = (_Float16)W1[u];
}

// ---- attention partial: R9 flash structure (organic pipeline, proven fastest)
// + native v_exp_f32 (FEXP2, no libm fixups) + full-rank LDS swizzle (262K
// conflicts vs 1.31M with rl&7) + stride-66 epilogue.
// Block = 64 rows x 2048 cols, 8 waves = 2 row-groups x 4 col-quarters.
// writes pv[ch][h][n][64] f32 and pl[ch][h][n] f32
__global__ __launch_bounds__(512) void k_attn(const float* __restrict__ fs,
        const float* __restrict__ fd, const float* __restrict__ fdmax,
        const _Float16* __restrict__ whT, const unsigned char* __restrict__ bits,
        float* __restrict__ pv, float* __restrict__ pl) {
    __shared__ __align__(16) char smem[34304];  // 2x16KB stage; epilogue overlay
    const int ch = blockIdx.x & 1;
    const int rowblk = (blockIdx.x >> 1) & 63;
    const int h = blockIdx.x >> 7;
    const int row0 = rowblk << 6;               // 64 rows per block
    const int cb0 = ch << 11;                   // 2048-col half base
    const int tid = threadIdx.x;
    const int l = tid & 63, w = tid >> 6;       // 8 waves
    const int rl = l & 15, g = l >> 4;
    const int rg = w >> 2, cq = w & 3;          // row-group, col-quarter
    const int r0 = row0 + rg * 32 + rl;
    const int r1 = r0 + 16;
    const float fsr0 = fs[h * NN + r0], fsr1 = fs[h * NN + r1];
    const float fm = fdmax[h];
    const float su0 = fsr0 + fm, su1 = fsr1 + fm;
    const float m0 = fmaxf(su0, ALPHA * su0);   // upper bound of row max
    const float m1 = fmaxf(su1, ALPHA * su1);
    const float A0 = (fsr0 - m0) * LOG2E, B0 = (ALPHA * fsr0 - m0) * LOG2E;
    const float A1 = (fsr1 - m1) * LOG2E, B1 = (ALPHA * fsr1 - m1) * LOG2E;
    const float* fdp = fd + h * NN + cb0 + cq * 32 + g * 8;
    const unsigned char* bp0 = bits + (size_t)r0 * (NN / 8) + (cb0 >> 3) + cq * 4;
    const unsigned char* bp1 = bits + (size_t)r1 * (NN / 8) + (cb0 >> 3) + cq * 4;
    const _Float16* whb = whT + (size_t)h * DH * NN + cb0;

    // stage source (pre-swizzled global addr, linear LDS dest); FULL-RANK swz
    const int d0_ = tid >> 4, c0_ = tid & 15;
    const int d1_ = 32 + (tid >> 4), c1_ = tid & 15;
    const _Float16* src0 = whb + (size_t)d0_ * NN + 8 * (c0_ ^ (d0_ & 15));
    const _Float16* src1 = whb + (size_t)d1_ * NN + 8 * (c1_ ^ (d1_ & 15));
    char* dstA0 = smem + w * 1024;              // buf0, chunk0 wave base
    char* dstA1 = smem + 8192 + w * 1024;
    char* dstB0 = smem + 16384 + w * 1024;      // buf1
    char* dstB1 = smem + 16384 + 8192 + w * 1024;

    f32x4 acc0[4] = {{0,0,0,0},{0,0,0,0},{0,0,0,0},{0,0,0,0}};
    f32x4 acc1[4] = {{0,0,0,0},{0,0,0,0},{0,0,0,0},{0,0,0,0}};
    f32x4 al0 = {0,0,0,0}, al1 = {0,0,0,0};
    f16x8 ones;
#pragma unroll
    for (int i = 0; i < 8; ++i) ones[i] = (_Float16)1.0f;
    const int rdswz = ((((cq << 2) | g) ^ rl) << 4);   // full-rank, 16B slots

    // ---- prologue: stage tile 0 into buf0; prefetch regsA (tile 0) ----
    gload_lds16(src0, dstA0);
    gload_lds16(src1, dstA1);
    float4 faA = *(const float4*)(fdp);
    float4 fbA = *(const float4*)(fdp + 4);
    unsigned int mA0 = *(const unsigned int*)(bp0);
    unsigned int mA1 = *(const unsigned int*)(bp1);
    float4 faB, fbB;
    unsigned int mB0, mB1;
    __syncthreads();

#define COMPUTE(BUF, FA, FB, M0v, M1v)                                          \
    {                                                                           \
        const float fv[8] = {FA.x, FA.y, FA.z, FA.w, FB.x, FB.y, FB.z, FB.w};   \
        f16x8 av0, av1;                                                         \
        const int sh = g << 3;                                                  \
        _Pragma("unroll")                                                       \
        for (int i = 0; i < 8; i += 2) {                                        \
            float ta = fmaxf(fmaf(fv[i], LOG2E, A0), fmaf(fv[i], ALPHA * LOG2E, B0)); \
            ta = ((M0v >> (sh + i)) & 1u) ? ta : -1e30f;                        \
            float tb = fmaxf(fmaf(fv[i+1], LOG2E, A0), fmaf(fv[i+1], ALPHA * LOG2E, B0)); \
            tb = ((M0v >> (sh + i + 1)) & 1u) ? tb : -1e30f;                    \
            fp16x2 p0 = __builtin_amdgcn_cvt_pkrtz(FEXP2(ta), FEXP2(tb));       \
            av0[i] = (_Float16)p0[0]; av0[i+1] = (_Float16)p0[1];               \
            float tc = fmaxf(fmaf(fv[i], LOG2E, A1), fmaf(fv[i], ALPHA * LOG2E, B1)); \
            tc = ((M1v >> (sh + i)) & 1u) ? tc : -1e30f;                        \
            float td = fmaxf(fmaf(fv[i+1], LOG2E, A1), fmaf(fv[i+1], ALPHA * LOG2E, B1)); \
            td = ((M1v >> (sh + i + 1)) & 1u) ? td : -1e30f;                    \
            fp16x2 p1 = __builtin_amdgcn_cvt_pkrtz(FEXP2(tc), FEXP2(td));       \
            av1[i] = (_Float16)p1[0]; av1[i+1] = (_Float16)p1[1];               \
        }                                                                       \
        al0 = __builtin_amdgcn_mfma_f32_16x16x32_f16(av0, ones, al0, 0, 0, 0);  \
        al1 = __builtin_amdgcn_mfma_f32_16x16x32_f16(av1, ones, al1, 0, 0, 0);  \
        _Pragma("unroll")                                                       \
        for (int t4 = 0; t4 < 4; ++t4) {                                        \
            f16x8 bv = *(const f16x8*)((BUF) + ((16 * t4 + rl) << 8) + rdswz);  \
            acc0[t4] = __builtin_amdgcn_mfma_f32_16x16x32_f16(av0, bv, acc0[t4], 0, 0, 0); \
            acc1[t4] = __builtin_amdgcn_mfma_f32_16x16x32_f16(av1, bv, acc1[t4], 0, 0, 0); \
        }                                                                       \
    }

#pragma unroll 1
    for (int k = 0; k < 8; ++k) {
        const int tB = 2 * k + 1;               // odd tile -> buf1 / regsB
        gload_lds16(src0 + tB * 128, dstB0);
        gload_lds16(src1 + tB * 128, dstB1);
        faB = *(const float4*)(fdp + tB * 128);
        fbB = *(const float4*)(fdp + tB * 128 + 4);
        mB0 = *(const unsigned int*)(bp0 + tB * 16);
        mB1 = *(const unsigned int*)(bp1 + tB * 16);
        COMPUTE(smem, faA, fbA, mA0, mA1);       // tile 2k from buf0
        __syncthreads();                         // buf1 staged; buf0 free
        if (k < 7) {
            const int tA = 2 * k + 2;
            gload_lds16(src0 + tA * 128, dstA0);
            gload_lds16(src1 + tA * 128, dstA1);
            faA = *(const float4*)(fdp + tA * 128);
            fbA = *(const float4*)(fdp + tA * 128 + 4);
            mA0 = *(const unsigned int*)(bp0 + tA * 16);
            mA1 = *(const unsigned int*)(bp1 + tA * 16);
        }
        COMPUTE((smem + 16384), faB, fbB, mB0, mB1);   // tile 2k+1 from buf1
        __syncthreads();                         // buf0 staged; buf1 free
    }
#undef COMPUTE

    // ---- epilogue: two passes (row-group p), stride-66 staging, 4-way cq reduce
    float* red = (float*)smem;                   // [4 cq][32 rows][66]
    float* lred = (float*)(smem + 33792);        // [4 cq][32 rows]
#pragma unroll
    for (int p = 0; p < 2; ++p) {
        if (rg == p) {
#pragma unroll
            for (int t4 = 0; t4 < 4; ++t4)
#pragma unroll
                for (int i = 0; i < 4; ++i) {
                    red[(cq * 32 + 4 * g + i) * 66 + 16 * t4 + rl]      = acc0[t4][i];
                    red[(cq * 32 + 16 + 4 * g + i) * 66 + 16 * t4 + rl] = acc1[t4][i];
                }
            if (rl == 0) {
#pragma unroll
                for (int i = 0; i < 4; ++i) {
                    lred[cq * 32 + 4 * g + i]      = al0[i];
                    lred[cq * 32 + 16 + 4 * g + i] = al1[i];
                }
            }
        }
        __syncthreads();
#pragma unroll
        for (int j = 0; j < 4; ++j) {
            const int R = w * 4 + j;             // 8 waves x 4 = 32 rows
            float v = 0.f, L = 0.f;
#pragma unroll
            for (int cc = 0; cc < 4; ++cc) {
                v += red[(cc * 32 + R) * 66 + l];
                L += lred[cc * 32 + R];
            }
            const int Rg = row0 + p * 32 + R;
            pv[(((size_t)(ch * NH + h) * NN) + Rg) * 64 + l] = v;
            if (l == 0) pl[(size_t)(ch * NH + h) * NN + Rg] = L;
        }
        __syncthreads();
    }
}

// ---- merge halves; MODE 0 -> h16 [n][H*DH] f16 ; MODE 1 -> head-mean out f32 ----
template<int MODE>
__global__ __launch_bounds__(256) void k_merge(const float* __restrict__ pv,
        const float* __restrict__ pl, void* __restrict__ outp) {
    int t = blockIdx.x * 256 + threadIdx.x;
    if (MODE == 0) {
        int d = t & 63, n = (t >> 6) & (NN - 1), h = t >> 18;
        float v = pv[((size_t)h * NN + n) * 64 + d] + pv[((size_t)(NH + h) * NN + n) * 64 + d];
        float L = pl[h * NN + n] + pl[NH * NN + h * NN + n];
        float o = v * __builtin_amdgcn_rcpf(L);
        o = o > 0.f ? o : __expf(o) - 1.f;
        ((_Float16*)outp)[(size_t)n * (NH * DH) + h * DH + d] = (_Float16)o;
    } else {
        int d = t & 63, n = t >> 6;
        float s = 0.f;
#pragma unroll
        for (int h = 0; h < NH; ++h) {
            float v = pv[((size_t)h * NN + n) * 64 + d] + pv[((size_t)(NH + h) * NN + n) * 64 + d];
            float L = pl[h * NN + n] + pl[NH * NN + h * NN + n];
            float o = v * __builtin_amdgcn_rcpf(L);
            s += o > 0.f ? o : __expf(o) - 1.f;
        }
        ((float*)outp)[t] = 0.25f * s;
    }
}

// ---- layer1 Wh via MFMA + fs/fd (no atomics); writes whT1 ----
__global__ __launch_bounds__(256) void k_l1wh(const _Float16* __restrict__ h16,
        const _Float16* __restrict__ w1T, const float* __restrict__ a1,
        _Float16* __restrict__ whT, float* __restrict__ fs, float* __restrict__ fd) {
    __shared__ float red[4][16][64];
    __shared__ _Float16 lt[16][64];
    int h = blockIdx.x >> 8;
    int row0 = (blockIdx.x & 255) << 4;
    int tid = threadIdx.x;
    int l = tid & 63, w = tid >> 6;
    int rl = l & 15, g = l >> 4;
    f32x4 acc[4] = {{0,0,0,0},{0,0,0,0},{0,0,0,0},{0,0,0,0}};
    const _Float16* ap = h16 + (size_t)(row0 + rl) * (NH * DH) + w * 64;
    const _Float16* bp = w1T + ((size_t)h * DH << 8) + w * 64;
#pragma unroll
    for (int j = 0; j < 2; ++j) {
        int fb = j * 32 + 8 * g;
        f16x8 avv = *(const f16x8*)(ap + fb);
#pragma unroll
        for (int t4 = 0; t4 < 4; ++t4) {
            f16x8 bv = *(const f16x8*)(bp + ((size_t)(16 * t4 + rl) << 8) + fb);
            acc[t4] = __builtin_amdgcn_mfma_f32_16x16x32_f16(avv, bv, acc[t4], 0, 0, 0);
        }
    }
#pragma unroll
    for (int t4 = 0; t4 < 4; ++t4)
#pragma unroll
        for (int i = 0; i < 4; ++i) red[w][t4 * 4 + i][l] = acc[t4][i];
    __syncthreads();
#pragma unroll
    for (int i = 0; i < 4; ++i) {
        float v = red[0][w * 4 + i][l] + red[1][w * 4 + i][l]
                + red[2][w * 4 + i][l] + red[3][w * 4 + i][l];
        lt[4 * g + i][16 * w + rl] = (_Float16)v;
    }
    __syncthreads();
    int d = tid & 63, rb = tid >> 6;
    f16x4 o;
#pragma unroll
    for (int j = 0; j < 4; ++j) o[j] = lt[rb * 4 + j][d];
    *(f16x4*)(whT + (size_t)(h * DH + d) * NN + row0 + rb * 4) = o;
    float as_ = a1[h * 2 * DH + d], ad_ = a1[h * 2 * DH + DH + d];
    float svj[4], dvj[4];
#pragma unroll
    for (int j = 0; j < 4; ++j) {
        float wv = (float)lt[rb * 4 + j][d];
        svj[j] = wv * as_;
        dvj[j] = wv * ad_;
    }
#pragma unroll
    for (int off = 1; off <= 32; off <<= 1) {
#pragma unroll
        for (int j = 0; j < 4; ++j) {
            svj[j] += __shfl_xor(svj[j], off);
            dvj[j] += __shfl_xor(dvj[j], off);
        }
    }
    if (d == 0) {
#pragma unroll
        for (int j = 0; j < 4; ++j) {
            fs[h * NN + row0 + rb * 4 + j] = svj[j];
            fd[h * NN + row0 + rb * 4 + j] = dvj[j];
        }
    }
}

extern "C" void kernel_launch(void* const* d_in, const int* in_sizes, int n_in,
                              void* d_out, int out_size, void* d_ws, size_t ws_size,
                              hipStream_t stream) {
    const float* x  = (const float*)d_in[0];
    const int* adj  = (const int*)d_in[1];
    const float* W0 = (const float*)d_in[2];
    const float* a0 = (const float*)d_in[3];
    const float* W1 = (const float*)d_in[4];
    const float* a1 = (const float*)d_in[5];
    float* out = (float*)d_out;
    char* ws = (char*)d_ws;

    unsigned char* bits = (unsigned char*)(ws);                        // 2MB
    _Float16* whT0 = (_Float16*)(ws + (2ull << 20));                   // 2MB
    _Float16* h16  = (_Float16*)(ws + (4ull << 20));                   // 2MB
    _Float16* w1T  = (_Float16*)(ws + (6ull << 20));                   // 128KB
    _Float16* whT1 = (_Float16*)(ws + (6ull << 20) + (256ull << 10));  // 2MB
    float* fs0  = (float*)(ws + (9ull << 20));
    float* fd0  = fs0 + NH * NN;
    float* fs1  = fd0 + NH * NN;
    float* fd1  = fs1 + NH * NN;
    float* fdm0 = fd1 + NH * NN;   // 8 floats
    float* fdm1 = fdm0 + 8;
    float* pv   = (float*)(ws + (10ull << 20));                        // 8MB
    float* pl   = (float*)(ws + (18ull << 20));                        // 128KB

    k_pack<<<NN * NN / 8 / 256, 256, 0, stream>>>(adj, bits);
    k_w1t<<<(NH * NH * DH * DH) / 256, 256, 0, stream>>>(W1, w1T);
    k_l0wh<<<NN / 16, 256, 0, stream>>>(x, W0, a0, whT0, fs0, fd0);
    k_fdmax<<<NH, 256, 0, stream>>>(fd0, fdm0);
    k_attn<<<2 * NH * (NN / 64), 512, 0, stream>>>(fs0, fd0, fdm0, whT0, bits, pv, pl);
    k_merge<0><<<(NH * NN * DH) / 256, 256, 0, stream>>>(pv, pl, h16);
    k_l1wh<<<NH * (NN / 16), 256, 0, stream>>>(h16, w1T, a1, whT1, fs1, fd1);
    k_fdmax<<<NH, 256, 0, stream>>>(fd1, fdm1);
    k_attn<<<2 * NH * (NN / 64), 512, 0, stream>>>(fs1, fd1, fdm1, whT1, bits, pv, pl);
    k_merge<1><<<(NN * DH) / 256, 256, 0, stream>>>(pv, pl, out);
}